// Round 9
// baseline (127.243 us; speedup 1.0000x reference)
//
#include <hip/hip_runtime.h>
#include <hip/hip_bf16.h>
#include <math.h>

#define T_SEQ 4096
#define NBATCH 4
#define C_EMB 512
#define HEAD 64
#define CHUNK 8                  // k-tiles (of 64) per attn job
#define EPB 144                  // per batch: sum over Q of ceil((2Q+2)/8), Q=0..31
#define NJOBS (NBATCH * EPB)     // 576

typedef __attribute__((ext_vector_type(8))) short short8;
typedef __attribute__((ext_vector_type(4))) short short4v;
typedef __attribute__((ext_vector_type(4))) float f32x4;

// scale folded into q at projection: exp(s/sqrt(512)) = exp2(qhat . k)
#define C2 (0.044194173824159216f * 1.44269504088896340736f)

__device__ __forceinline__ unsigned short f2bf(float f) {
    union { float f; unsigned u; } v; v.f = f;
    unsigned u = v.u;
    u += 0x7FFF + ((u >> 16) & 1);   // round-to-nearest-even
    return (unsigned short)(u >> 16);
}
// packed f32x2 -> bf16x2 (v_cvt_pk_bf16_f32); low 16 = a, high 16 = b
__device__ __forceinline__ unsigned pk2bf(float a, float b) {
    __hip_bfloat162 h = __float22bfloat162_rn(make_float2(a, b));
    return *(unsigned*)&h;
}
__device__ __forceinline__ float bf2f(unsigned short u) {
    union { unsigned u; float f; } v; v.u = ((unsigned)u) << 16;
    return v.f;
}

// async global->LDS, 16 B per lane; LDS dest = wave-uniform base + lane*16
#define GLD_LDS16(gp, lp)                                                     \
    __builtin_amdgcn_global_load_lds(                                         \
        (const __attribute__((address_space(1))) void*)(gp),                  \
        (__attribute__((address_space(3))) void*)(lp), 16, 0, 0)

// ---------------- W conversion: emit the per-chunk LDS image ------------------
// wt2 short index: (((c*12 + tile)*2 + kc)*64 + lane)*8 + i  holds
// bf16(W_w[k][n]), w=tile>>2, n=(tile&3)*16+(lane&15), k=c*64+kc*32+(lane>>4)*8+i.
// Also zeroes the attn work-queue ticket (stream-ordered, re-poison-safe).
__global__ __launch_bounds__(64) void wcvt_kernel(
    const float* __restrict__ Wq, const float* __restrict__ Wk,
    const float* __restrict__ Wv, unsigned short* __restrict__ wt2,
    int* __restrict__ ticket)
{
    const int gid  = blockIdx.x * 64 + threadIdx.x;   // 0..12287
    if (gid == 0) *ticket = 0;
    const int lane = gid & 63;
    int rest = gid >> 6;
    const int kc   = rest & 1; rest >>= 1;
    const int tile = rest % 12;
    const int c    = rest / 12;
    const float* W = (tile < 4) ? Wq : (tile < 8) ? Wk : Wv;
    const int n  = (tile & 3) * 16 + (lane & 15);
    const int k0 = c * 64 + kc * 32 + (lane >> 4) * 8;
    unsigned short tmp[8];
#pragma unroll
    for (int i = 0; i < 8; ++i) tmp[i] = f2bf(W[(size_t)(k0 + i) * HEAD + n]);
    *(short8*)(wt2 + (size_t)gid * 8) = *(short8*)tmp;
}

// ---------------- Projection v5: global_load_lds W staging --------------------
__global__ __launch_bounds__(512, 4) void proj_kernel(
    const float* __restrict__ x,            // [16384, 512]
    const unsigned short* __restrict__ wt2, // [8][12][2][64][8] bf16
    unsigned short* __restrict__ qout,      // [16384, 64]  (pre-scaled by C2)
    unsigned short* __restrict__ kout,      // [16384, 64]
    unsigned short* __restrict__ vt)        // [4][64][4096]
{
    __shared__ unsigned short Wl[2][12288];     // 49152 B, per-chunk image
    __shared__ unsigned short Xl[2][32][72];    //  9216 B (reused as Vsh[64][40])

    const int tid  = threadIdx.x;
    const int wave = tid >> 6;
    const int lane = tid & 63;
    const int l16  = lane & 15;
    const int quad = lane >> 4;
    const int row0 = blockIdx.x * 32;
    const int mq   = wave & 1;           // M-quarter (16 rows)
    const int ng   = wave >> 1;          // N-group: tiles ng*3 .. ng*3+2

    const bool xst = tid < 256;
    const int xrow = tid >> 3;           // x row (tid<256)
    const int xc8  = (tid & 7) * 8;

    f32x4 acc[3];
#pragma unroll
    for (int j = 0; j < 3; ++j) acc[j] = (f32x4){0.f, 0.f, 0.f, 0.f};

    // ---- stage chunk 0 into buffer 0 ----
#pragma unroll
    for (int m = 0; m < 3; ++m)
        GLD_LDS16(wt2 + (size_t)(m * 4096 + wave * 512 + lane * 8),
                  &Wl[0][m * 4096 + wave * 512]);
    if (xst) {
        const float* xs = x + (size_t)(row0 + xrow) * C_EMB + xc8;
        float4 a = *(const float4*)(xs);
        float4 b = *(const float4*)(xs + 4);
        int4 ai = make_int4((int)pk2bf(a.x, a.y), (int)pk2bf(a.z, a.w),
                            (int)pk2bf(b.x, b.y), (int)pk2bf(b.z, b.w));
        *(short8*)&Xl[0][xrow][xc8] = *(short8*)&ai;
    }
    __syncthreads();

    for (int c = 0; c < 8; ++c) {
        const int bb = c & 1;
        if (c < 7) {                     // stage chunk c+1 into other buffer
            const int nb = bb ^ 1;
            const size_t g0 = (size_t)(c + 1) * 12288;
#pragma unroll
            for (int m = 0; m < 3; ++m)
                GLD_LDS16(wt2 + g0 + (size_t)(m * 4096 + wave * 512 + lane * 8),
                          &Wl[nb][m * 4096 + wave * 512]);
            if (xst) {
                const float* xs = x + (size_t)(row0 + xrow) * C_EMB + (c + 1) * 64 + xc8;
                float4 a = *(const float4*)(xs);
                float4 b = *(const float4*)(xs + 4);
                int4 ai = make_int4((int)pk2bf(a.x, a.y), (int)pk2bf(a.z, a.w),
                                    (int)pk2bf(b.x, b.y), (int)pk2bf(b.z, b.w));
                *(short8*)&Xl[nb][xrow][xc8] = *(short8*)&ai;
            }
        }

        // compute on buffer bb: 2 kc x (1 A-frag, 3 B-frags, 3 MFMA)
#pragma unroll
        for (int kc = 0; kc < 2; ++kc) {
            short8 a0 = *(const short8*)&Xl[bb][mq * 16 + l16][kc * 32 + quad * 8];
#pragma unroll
            for (int j = 0; j < 3; ++j) {
                const int ct = ng * 3 + j;
                short8 bfr = *(const short8*)&Wl[bb][(ct * 128 + kc * 64 + lane) * 8];
                acc[j] = __builtin_amdgcn_mfma_f32_16x16x32_bf16(a0, bfr, acc[j], 0, 0, 0);
            }
        }
        __syncthreads();
    }

    // epilogue: wave owns (mq, tiles ng*3..ng*3+2); tile ct: m=ct>>2, n=ct&3
    unsigned short (*Vsh)[40] = (unsigned short (*)[40]) & Xl[0][0][0];  // 5120 B
#pragma unroll
    for (int j = 0; j < 3; ++j) {
        const int ct = ng * 3 + j;
        const int m  = ct >> 2;
        const int n  = ct & 3;
#pragma unroll
        for (int r = 0; r < 4; ++r) {
            const int row = row0 + mq * 16 + quad * 4 + r;
            if (m == 0)
                qout[(size_t)row * HEAD + n * 16 + l16] = f2bf(acc[j][r] * C2);
            else if (m == 1)
                kout[(size_t)row * HEAD + n * 16 + l16] = f2bf(acc[j][r]);
            else
                Vsh[n * 16 + l16][mq * 16 + quad * 4 + r] = f2bf(acc[j][r]);
        }
    }
    __syncthreads();
    if (tid < 256) {
        int h  = tid >> 2;
        int tc = (tid & 3) * 8;
        int b  = row0 >> 12;
        int t0 = row0 & (T_SEQ - 1);
        unsigned short* dst = vt + ((size_t)(b * HEAD + h)) * T_SEQ + t0 + tc;
        *(short8*)dst = *(const short8*)&Vsh[h][tc];
    }
}

// stage one V row-chunk (8 cols from vc, vc multiple of 8) phi-swizzled:
// col c bits [s|d|q1 q0|r1 r0] -> position [s|q1 q0|d|r1 r0]
__device__ __forceinline__ void stage_v8(unsigned short (*Vbuf)[72], int sr, int pos0,
                                         short8 v0) {
    *(short4v*)&Vbuf[sr][pos0]     = __builtin_shufflevector(v0, v0, 0, 1, 2, 3);
    *(short4v*)&Vbuf[sr][pos0 + 8] = __builtin_shufflevector(v0, v0, 4, 5, 6, 7);
}

// ---------------- Attention: persistent blocks + LPT work queue --------------
// 1024 blocks at 4 blocks/CU (launch_bounds(512,8): VGPR<=64, LDS 37.4KB*4 =
// 149.5 <= 160 KB) -> 32 waves/CU for latency hiding of the per-iteration
// barrier drain. Jobs pulled longest-first from a global atomic ticket; job
// body = verified round-2 structure. No fences: ticket is distribution only,
// partials land at canonical pids consumed by a separate combine kernel.
__global__ __launch_bounds__(512, 8) void attn1_kernel(
    const unsigned short* __restrict__ qb,  // [B*T, 64] pre-scaled
    const unsigned short* __restrict__ kb,  // [B*T, 64]
    const unsigned short* __restrict__ vt,  // [4][64][4096]
    unsigned short* __restrict__ po,        // [576][128][64] bf16 partials
    float* __restrict__ pl,                 // [576][128]
    int* __restrict__ ticket,               // work-queue counter (zeroed)
    float* __restrict__ out)                // [4][4096][64]
{
    __shared__ unsigned short Ks[2][64][72];    // [buf][kpos][h]
    __shared__ unsigned short Vs[2][64][72];    // [buf][h][phi(kpos)]
    __shared__ int sh_t;

    const int tid  = threadIdx.x;
    const int wave = tid >> 6;            // 0..7
    const int lane = tid & 63;
    const int l16  = lane & 15;
    const int quad = lane >> 4;

    // staging role: 512 threads, each 16 B of K and 16 B of V per tile
    const int sr   = tid >> 3;            // 0..63 (K k-row / V h-row)
    const int scK  = (tid & 7) * 8;       // K col (h) 0..56
    const int vc   = scK;                 // V col (kpos chunk)
    const int pos0 = (vc & 32) + ((vc & 8) << 1) + ((vc & 16) >> 2);

    for (;;) {
        if (tid == 0) sh_t = atomicAdd(ticket, 1);
        __syncthreads();                 // publishes sh_t; guards LDS reuse
        const int t = sh_t;
        if (t >= NJOBS) break;

        const int b = t & 3;             // interleave batches: global LPT
        const int r = t >> 2;            // LPT rank 0..143
        int Q, c;
        if (r < 112) {                   // full (np=8) chunks
            int g = 1;
#pragma unroll
            for (int gg = 2; gg <= 7; ++gg) if (r >= 2 * gg * (gg - 1)) g = gg;
            const int rem = r - 2 * g * (g - 1);   // 0..4g-1
            Q = 4 * g + rem / g;
            c = rem % g;
        } else {                         // tail chunks: np = 8,6,4,2
            const int band = (r - 112) >> 3;
            const int g = (r - 112) & 7;
            Q = 4 * g + (3 - band);
            c = g;
        }
        const int gQ = Q >> 2;
        const int nc = gQ + 1;
        const int e0 = 2 * gQ * (gQ + 1) + (Q & 3) * (gQ + 1);

        const size_t base = (size_t)b * T_SEQ;
        const int qrow0 = Q * 128 + wave * 16;      // wave's first q-row
        const int qrow  = qrow0 + l16;
        short8 aq0 = *(const short8*)(qb + (base + qrow) * HEAD + quad * 8);
        short8 aq1 = *(const short8*)(qb + (base + qrow) * HEAD + 32 + quad * 8);

        float lacc = 0.f;
        f32x4 o[4];
#pragma unroll
        for (int n = 0; n < 4; ++n) o[n] = (f32x4){0.f, 0.f, 0.f, 0.f};

        const int nk  = 2 * Q + 2;                  // causal k-tiles
        const int kt0 = c * CHUNK;
        const int np  = min(CHUNK, nk - kt0);       // 2..8 iterations

        short8 kra, vra;
        {
            const int kbase = kt0 * 64;
            kra = *(const short8*)(kb + (base + kbase + sr) * HEAD + scK);
            vra = *(const short8*)(vt + ((size_t)(b * HEAD + sr)) * T_SEQ + kbase + vc);
        }
        *(short8*)&Ks[0][sr][scK] = kra;
        stage_v8(Vs[0], sr, pos0, vra);

        for (int p = 0; p < np; ++p) {
            const int cur = p & 1;
            const int kbase = (kt0 + p) * 64;
            __syncthreads();             // LDS[cur] ready; prev-iter reads done

            if (p + 1 < np) {            // prefetch next tile into regs
                const int nb = kbase + 64;
                kra = *(const short8*)(kb + (base + nb + sr) * HEAD + scK);
                vra = *(const short8*)(vt + ((size_t)(b * HEAD + sr)) * T_SEQ + nb + vc);
            }

            // wave-level early-out: tile fully beyond this wave's causal range
            const bool live = (kbase <= qrow0 + 15);
            if (live) {
                // S^T = K.Q^T: lane gets S[q=l16][c = kbase + n*16 + quad*4 + r]
                f32x4 s[4];
                __builtin_amdgcn_s_setprio(1);   // T5: favor MFMA waves
#pragma unroll
                for (int n = 0; n < 4; ++n) {
                    short8 bk0 = *(const short8*)&Ks[cur][n * 16 + l16][quad * 8];
                    short8 bk1 = *(const short8*)&Ks[cur][n * 16 + l16][32 + quad * 8];
                    f32x4 accS = (f32x4){0.f, 0.f, 0.f, 0.f};
                    accS = __builtin_amdgcn_mfma_f32_16x16x32_bf16(bk0, aq0, accS, 0, 0, 0);
                    accS = __builtin_amdgcn_mfma_f32_16x16x32_bf16(bk1, aq1, accS, 0, 0, 0);
                    s[n] = accS;
                }
                __builtin_amdgcn_s_setprio(0);

                // P = exp2(S); zero masked cols on diagonal tiles
#pragma unroll
                for (int n = 0; n < 4; ++n)
#pragma unroll
                    for (int rr = 0; rr < 4; ++rr)
                        s[n][rr] = __builtin_amdgcn_exp2f(s[n][rr]);

                if (kbase + 63 > qrow0) {
                    const int cb = kbase + quad * 4;
#pragma unroll
                    for (int n = 0; n < 4; ++n)
#pragma unroll
                        for (int rr = 0; rr < 4; ++rr)
                            if (cb + n * 16 + rr > qrow) s[n][rr] = 0.f;
                }

#pragma unroll
                for (int n = 0; n < 4; ++n)
                    lacc += (s[n][0] + s[n][1]) + (s[n][2] + s[n][3]);

                // PV: pack A-frag (k-order matches phi-swizzled V), B = b128
#pragma unroll
                for (int st = 0; st < 2; ++st) {
                    int4 ai = make_int4(
                        (int)pk2bf(s[2 * st][0],     s[2 * st][1]),
                        (int)pk2bf(s[2 * st][2],     s[2 * st][3]),
                        (int)pk2bf(s[2 * st + 1][0], s[2 * st + 1][1]),
                        (int)pk2bf(s[2 * st + 1][2], s[2 * st + 1][3]));
                    short8 af = *(short8*)&ai;
                    __builtin_amdgcn_s_setprio(1);
#pragma unroll
                    for (int n = 0; n < 4; ++n) {
                        short8 bv = *(const short8*)&Vs[cur][n * 16 + l16][32 * st + quad * 8];
                        o[n] = __builtin_amdgcn_mfma_f32_16x16x32_bf16(af, bv, o[n], 0, 0, 0);
                    }
                    __builtin_amdgcn_s_setprio(0);
                }
            }

            if (p + 1 < np) {            // stage next tile into the other buffer
                const int nxt = cur ^ 1;
                *(short8*)&Ks[nxt][sr][scK] = kra;
                stage_v8(Vs[nxt], sr, pos0, vra);
            }
        }

        // reduce l over the quad dimension (q-row = l16 per lane)
        lacc += __shfl_xor(lacc, 16);
        lacc += __shfl_xor(lacc, 32);

        if (nc == 1) {
            // single-chunk job (Q<4): normalize in-register, write out directly
            float invr[4];
#pragma unroll
            for (int rr = 0; rr < 4; ++rr)
                invr[rr] = 1.f / __shfl(lacc, quad * 4 + rr);
#pragma unroll
            for (int n = 0; n < 4; ++n)
#pragma unroll
                for (int rr = 0; rr < 4; ++rr) {
                    const int row = qrow0 + quad * 4 + rr;
                    out[((size_t)(b * T_SEQ + row)) * HEAD + n * 16 + l16] =
                        o[n][rr] * invr[rr];
                }
            continue;
        }

        // multi-chunk: write partials at canonical pid
        const int pid = b * EPB + e0 + c;
#pragma unroll
        for (int n = 0; n < 4; ++n)
#pragma unroll
            for (int rr = 0; rr < 4; ++rr) {
                int lr = wave * 16 + quad * 4 + rr;          // 0..127
                po[(size_t)pid * 8192 + lr * 64 + n * 16 + l16] = f2bf(o[n][rr]);
            }
        if (quad == 0)
            pl[pid * 128 + wave * 16 + l16] = lacc;
    }
}

// ---------------- Combine: sum partials for Q>=4, normalize ------------------
// canonical pids: pid0 = b*EPB + e0(Q), chunk cc at pid0+cc. 448 blocks x 256.
__global__ __launch_bounds__(256) void combine_kernel(
    const unsigned short* __restrict__ po, const float* __restrict__ pl,
    float* __restrict__ out)
{
    const int gth  = blockIdx.x * 256 + threadIdx.x;  // octet idx, 114688 total
    const int h8   = gth & 7;
    const int rowi = gth >> 3;           // 0..14335
    const int lr   = rowi & 127;
    const int Qi   = (rowi >> 7) % 28;
    const int b    = (rowi >> 7) / 28;
    const int Q    = Qi + 4;
    const int g    = Q >> 2;
    const int nc   = g + 1;
    const int e0   = 2 * g * (g + 1) + (Q & 3) * (g + 1);
    const int pid0 = b * EPB + e0;

    float l = 0.f;
    float acc[8];
#pragma unroll
    for (int i = 0; i < 8; ++i) acc[i] = 0.f;
    for (int cc = 0; cc < nc; ++cc) {
        l += pl[(pid0 + cc) * 128 + lr];
        short8 p8 = *(const short8*)(po + (size_t)(pid0 + cc) * 8192 + lr * 64 + h8 * 8);
#pragma unroll
        for (int i = 0; i < 8; ++i) acc[i] += bf2f((unsigned short)p8[i]);
    }
    float inv = 1.f / l;
    float* dst = out + ((size_t)(b * T_SEQ + Q * 128 + lr)) * HEAD + h8 * 8;
    *(float4*)dst       = make_float4(acc[0] * inv, acc[1] * inv, acc[2] * inv, acc[3] * inv);
    *(float4*)(dst + 4) = make_float4(acc[4] * inv, acc[5] * inv, acc[6] * inv, acc[7] * inv);
}

extern "C" void kernel_launch(void* const* d_in, const int* in_sizes, int n_in,
                              void* d_out, int out_size, void* d_ws, size_t ws_size,
                              hipStream_t stream) {
    const float* x  = (const float*)d_in[0];
    const float* Wq = (const float*)d_in[1];
    const float* Wk = (const float*)d_in[2];
    const float* Wv = (const float*)d_in[3];
    float* out = (float*)d_out;

    char* ws = (char*)d_ws;
    unsigned short* qb = (unsigned short*)(ws);                 // 2 MB
    unsigned short* kb = (unsigned short*)(ws + (2u << 20));    // 2 MB
    unsigned short* vt = (unsigned short*)(ws + (4u << 20));    // 2 MB
    unsigned short* wt2 = (unsigned short*)(ws + (6u << 20));   // 192 KB
    float* pl = (float*)(ws + (6u << 20) + 196608);             // 294912 B
    int* ticket = (int*)(ws + (6u << 20) + 196608 + 294912);    // 512 B slot
    unsigned short* po = (unsigned short*)(ws + (6u << 20) + 196608 + 294912 + 512); // 9.4 MB

    wcvt_kernel<<<dim3(192), dim3(64), 0, stream>>>(Wq, Wk, Wv, wt2, ticket);
    proj_kernel<<<dim3(512), dim3(512), 0, stream>>>(x, wt2, qb, kb, vt);
    attn1_kernel<<<dim3(1024), dim3(512), 0, stream>>>(qb, kb, vt, po, pl, ticket, out);
    combine_kernel<<<dim3(448), dim3(256), 0, stream>>>(po, pl, out);
}

// Round 10
// 110.577 us; speedup vs baseline: 1.1507x; 1.1507x over previous
//
#include <hip/hip_runtime.h>
#include <hip/hip_bf16.h>
#include <math.h>

#define T_SEQ 4096
#define NBATCH 4
#define C_EMB 512
#define HEAD 64
#define CHUNK 8                  // k-tiles (of 64) per attn phase-1 block
#define EPB 144                  // per batch: sum over Q of ceil((2Q+2)/8), Q=0..31

typedef __attribute__((ext_vector_type(8))) short short8;
typedef __attribute__((ext_vector_type(4))) short short4v;
typedef __attribute__((ext_vector_type(4))) float f32x4;

// scale folded into q at projection: exp(s/sqrt(512)) = exp2(qhat . k)
#define C2 (0.044194173824159216f * 1.44269504088896340736f)

__device__ __forceinline__ unsigned short f2bf(float f) {
    union { float f; unsigned u; } v; v.f = f;
    unsigned u = v.u;
    u += 0x7FFF + ((u >> 16) & 1);   // round-to-nearest-even
    return (unsigned short)(u >> 16);
}
// packed f32x2 -> bf16x2 (v_cvt_pk_bf16_f32); low 16 = a, high 16 = b
__device__ __forceinline__ unsigned pk2bf(float a, float b) {
    __hip_bfloat162 h = __float22bfloat162_rn(make_float2(a, b));
    return *(unsigned*)&h;
}
__device__ __forceinline__ float bf2f(unsigned short u) {
    union { unsigned u; float f; } v; v.u = ((unsigned)u) << 16;
    return v.f;
}

// async global->LDS, 16 B per lane; LDS dest = wave-uniform base + lane*16
#define GLD_LDS16(gp, lp)                                                     \
    __builtin_amdgcn_global_load_lds(                                         \
        (const __attribute__((address_space(1))) void*)(gp),                  \
        (__attribute__((address_space(3))) void*)(lp), 16, 0, 0)

// ---------------- W conversion: emit the per-chunk LDS image ------------------
// wt2 short index: (((c*12 + tile)*2 + kc)*64 + lane)*8 + i  holds
// bf16(W_w[k][n]), w=tile>>2, n=(tile&3)*16+(lane&15), k=c*64+kc*32+(lane>>4)*8+i.
// Lane's 16 B IS its MFMA B-fragment -> staged LDS reads are conflict-free.
__global__ __launch_bounds__(64) void wcvt_kernel(
    const float* __restrict__ Wq, const float* __restrict__ Wk,
    const float* __restrict__ Wv, unsigned short* __restrict__ wt2)
{
    const int gid  = blockIdx.x * 64 + threadIdx.x;   // 0..12287
    const int lane = gid & 63;
    int rest = gid >> 6;
    const int kc   = rest & 1; rest >>= 1;
    const int tile = rest % 12;
    const int c    = rest / 12;
    const float* W = (tile < 4) ? Wq : (tile < 8) ? Wk : Wv;
    const int n  = (tile & 3) * 16 + (lane & 15);
    const int k0 = c * 64 + kc * 32 + (lane >> 4) * 8;
    unsigned short tmp[8];
#pragma unroll
    for (int i = 0; i < 8; ++i) tmp[i] = f2bf(W[(size_t)(k0 + i) * HEAD + n]);
    *(short8*)(wt2 + (size_t)gid * 8) = *(short8*)tmp;
}

// ---------------- Projection v5: global_load_lds W staging --------------------
// grid 512 x 512thr; block = 32 x-rows, 2 blocks/CU (LDS 58.4 KB). 8 waves
// split 24 (M-quarter x N-tile) jobs; W chunk (24 KB) staged direct-to-LDS via
// 3 global_load_lds_dwordx4 per wave (no VGPR round-trip, conflict-free image).
__global__ __launch_bounds__(512, 4) void proj_kernel(
    const float* __restrict__ x,            // [16384, 512]
    const unsigned short* __restrict__ wt2, // [8][12][2][64][8] bf16
    unsigned short* __restrict__ qout,      // [16384, 64]  (pre-scaled by C2)
    unsigned short* __restrict__ kout,      // [16384, 64]
    unsigned short* __restrict__ vt)        // [4][64][4096]
{
    __shared__ unsigned short Wl[2][12288];     // 49152 B, per-chunk image
    __shared__ unsigned short Xl[2][32][72];    //  9216 B (reused as Vsh[64][40])

    const int tid  = threadIdx.x;
    const int wave = tid >> 6;
    const int lane = tid & 63;
    const int l16  = lane & 15;
    const int quad = lane >> 4;
    const int row0 = blockIdx.x * 32;
    const int mq   = wave & 1;           // M-quarter (16 rows)
    const int ng   = wave >> 1;          // N-group: tiles ng*3 .. ng*3+2

    const bool xst = tid < 256;
    const int xrow = tid >> 3;           // x row (tid<256)
    const int xc8  = (tid & 7) * 8;

    f32x4 acc[3];
#pragma unroll
    for (int j = 0; j < 3; ++j) acc[j] = (f32x4){0.f, 0.f, 0.f, 0.f};

    // ---- stage chunk 0 into buffer 0 ----
#pragma unroll
    for (int m = 0; m < 3; ++m)
        GLD_LDS16(wt2 + (size_t)(m * 4096 + wave * 512 + lane * 8),
                  &Wl[0][m * 4096 + wave * 512]);
    if (xst) {
        const float* xs = x + (size_t)(row0 + xrow) * C_EMB + xc8;
        float4 a = *(const float4*)(xs);
        float4 b = *(const float4*)(xs + 4);
        int4 ai = make_int4((int)pk2bf(a.x, a.y), (int)pk2bf(a.z, a.w),
                            (int)pk2bf(b.x, b.y), (int)pk2bf(b.z, b.w));
        *(short8*)&Xl[0][xrow][xc8] = *(short8*)&ai;
    }
    __syncthreads();

    for (int c = 0; c < 8; ++c) {
        const int bb = c & 1;
        if (c < 7) {                     // stage chunk c+1 into other buffer
            const int nb = bb ^ 1;
            const size_t g0 = (size_t)(c + 1) * 12288;
#pragma unroll
            for (int m = 0; m < 3; ++m)
                GLD_LDS16(wt2 + g0 + (size_t)(m * 4096 + wave * 512 + lane * 8),
                          &Wl[nb][m * 4096 + wave * 512]);
            if (xst) {
                const float* xs = x + (size_t)(row0 + xrow) * C_EMB + (c + 1) * 64 + xc8;
                float4 a = *(const float4*)(xs);
                float4 b = *(const float4*)(xs + 4);
                int4 ai = make_int4((int)pk2bf(a.x, a.y), (int)pk2bf(a.z, a.w),
                                    (int)pk2bf(b.x, b.y), (int)pk2bf(b.z, b.w));
                *(short8*)&Xl[nb][xrow][xc8] = *(short8*)&ai;
            }
        }

        // compute on buffer bb: 2 kc x (1 A-frag, 3 B-frags, 3 MFMA)
#pragma unroll
        for (int kc = 0; kc < 2; ++kc) {
            short8 a0 = *(const short8*)&Xl[bb][mq * 16 + l16][kc * 32 + quad * 8];
#pragma unroll
            for (int j = 0; j < 3; ++j) {
                const int ct = ng * 3 + j;
                short8 bfr = *(const short8*)&Wl[bb][(ct * 128 + kc * 64 + lane) * 8];
                acc[j] = __builtin_amdgcn_mfma_f32_16x16x32_bf16(a0, bfr, acc[j], 0, 0, 0);
            }
        }
        __syncthreads();
    }

    // epilogue: wave owns (mq, tiles ng*3..ng*3+2); tile ct: m=ct>>2, n=ct&3
    unsigned short (*Vsh)[40] = (unsigned short (*)[40]) & Xl[0][0][0];  // 5120 B
#pragma unroll
    for (int j = 0; j < 3; ++j) {
        const int ct = ng * 3 + j;
        const int m  = ct >> 2;
        const int n  = ct & 3;
#pragma unroll
        for (int r = 0; r < 4; ++r) {
            const int row = row0 + mq * 16 + quad * 4 + r;
            if (m == 0)
                qout[(size_t)row * HEAD + n * 16 + l16] = f2bf(acc[j][r] * C2);
            else if (m == 1)
                kout[(size_t)row * HEAD + n * 16 + l16] = f2bf(acc[j][r]);
            else
                Vsh[n * 16 + l16][mq * 16 + quad * 4 + r] = f2bf(acc[j][r]);
        }
    }
    __syncthreads();
    if (tid < 256) {
        int h  = tid >> 2;
        int tc = (tid & 3) * 8;
        int b  = row0 >> 12;
        int t0 = row0 & (T_SEQ - 1);
        unsigned short* dst = vt + ((size_t)(b * HEAD + h)) * T_SEQ + t0 + tc;
        *(short8*)dst = *(const short8*)&Vsh[h][tc];
    }
}

// stage one V row-chunk (8 cols from vc, vc multiple of 8) phi-swizzled:
// col c bits [s|d|q1 q0|r1 r0] -> position [s|q1 q0|d|r1 r0]
// pos0 = (vc&32) + ((vc&8)<<1) + ((vc&16)>>2); j=0..3 -> pos0+j, j=4..7 -> pos0+8+(j-4)
__device__ __forceinline__ void stage_v8(unsigned short (*Vbuf)[72], int sr, int pos0,
                                         short8 v0) {
    *(short4v*)&Vbuf[sr][pos0]     = __builtin_shufflevector(v0, v0, 0, 1, 2, 3);
    *(short4v*)&Vbuf[sr][pos0 + 8] = __builtin_shufflevector(v0, v0, 4, 5, 6, 7);
}

// ---------------- Attention phase 1: 128 q-rows/block, 8 waves ---------------
// S^T trick (lane holds S[q=l16][64 k-cols]), no P LDS round-trip. K/V LDS
// tiles are shared by 8 waves (128 q-rows) -> staging/barrier cost per MFMA
// is half the 4-wave version. LPT dispatch: long (np=8) blocks launch first.
__global__ __launch_bounds__(512, 4) void attn1_kernel(
    const unsigned short* __restrict__ qb,  // [B*T, 64] pre-scaled
    const unsigned short* __restrict__ kb,  // [B*T, 64]
    const unsigned short* __restrict__ vt,  // [4][64][4096]
    unsigned short* __restrict__ po,        // [576][128][64] bf16 partials
    float* __restrict__ pl)                 // [576][128]
{
    __shared__ unsigned short Ks[2][64][72];    // [buf][kpos][h]
    __shared__ unsigned short Vs[2][64][72];    // [buf][h][phi(kpos)]

    const int tid  = threadIdx.x;
    const int wave = tid >> 6;            // 0..7
    const int lane = tid & 63;
    const int l16  = lane & 15;
    const int quad = lane >> 4;

    const int b = blockIdx.x / EPB;
    const int e = (EPB - 1) - (blockIdx.x % EPB);   // LPT: big-np blocks first
    // decode e -> (Q, c): group g has Q in [4g,4g+4), nc=g+1, base 2g(g+1)
    int g = 0;
#pragma unroll
    for (int gg = 1; gg < 8; ++gg) if (e >= 2 * gg * (gg + 1)) g = gg;
    const int rem = e - 2 * g * (g + 1);
    const int t   = rem / (g + 1);
    const int c   = rem - t * (g + 1);
    const int Q   = 4 * g + t;            // q-tile of 128 rows, 0..31

    const size_t base = (size_t)b * T_SEQ;
    const int qrow0 = Q * 128 + wave * 16;      // wave's first q-row
    const int qrow  = qrow0 + l16;
    short8 aq0 = *(const short8*)(qb + (base + qrow) * HEAD + quad * 8);
    short8 aq1 = *(const short8*)(qb + (base + qrow) * HEAD + 32 + quad * 8);

    float lacc = 0.f;
    f32x4 o[4];
#pragma unroll
    for (int n = 0; n < 4; ++n) o[n] = (f32x4){0.f, 0.f, 0.f, 0.f};

    const int nk  = 2 * Q + 2;                  // causal k-tiles for this q-tile
    const int kt0 = c * CHUNK;
    const int np  = min(CHUNK, nk - kt0);       // 2..8 64-wide iterations

    // staging role: 512 threads, each 16 B of K and 16 B of V per tile
    const int sr   = tid >> 3;            // 0..63 (K k-row / V h-row)
    const int scK  = (tid & 7) * 8;       // K col (h) 0..56
    const int vc   = scK;                 // V col (kpos chunk)
    const int pos0 = (vc & 32) + ((vc & 8) << 1) + ((vc & 16) >> 2);

    short8 kra, vra;
    {
        const int kbase = kt0 * 64;
        kra = *(const short8*)(kb + (base + kbase + sr) * HEAD + scK);
        vra = *(const short8*)(vt + ((size_t)(b * HEAD + sr)) * T_SEQ + kbase + vc);
    }
    *(short8*)&Ks[0][sr][scK] = kra;
    stage_v8(Vs[0], sr, pos0, vra);

    for (int p = 0; p < np; ++p) {
        const int cur = p & 1;
        const int kbase = (kt0 + p) * 64;
        __syncthreads();                 // LDS[cur] ready; prev-iter reads done

        if (p + 1 < np) {                // prefetch next tile into regs
            const int nb = kbase + 64;
            kra = *(const short8*)(kb + (base + nb + sr) * HEAD + scK);
            vra = *(const short8*)(vt + ((size_t)(b * HEAD + sr)) * T_SEQ + nb + vc);
        }

        // wave-level early-out: whole tile beyond this wave's causal range
        const bool live = (kbase <= qrow0 + 15);
        if (live) {
            // S^T = K.Q^T: lane gets S[q=l16][c = kbase + n*16 + quad*4 + r]
            f32x4 s[4];
            __builtin_amdgcn_s_setprio(1);   // T5: favor MFMA waves
#pragma unroll
            for (int n = 0; n < 4; ++n) {
                short8 bk0 = *(const short8*)&Ks[cur][n * 16 + l16][quad * 8];
                short8 bk1 = *(const short8*)&Ks[cur][n * 16 + l16][32 + quad * 8];
                f32x4 accS = (f32x4){0.f, 0.f, 0.f, 0.f};
                accS = __builtin_amdgcn_mfma_f32_16x16x32_bf16(bk0, aq0, accS, 0, 0, 0);
                accS = __builtin_amdgcn_mfma_f32_16x16x32_bf16(bk1, aq1, accS, 0, 0, 0);
                s[n] = accS;
            }
            __builtin_amdgcn_s_setprio(0);

            // P = exp2(S); zero masked cols on diagonal tiles (wave-uniform test)
#pragma unroll
            for (int n = 0; n < 4; ++n)
#pragma unroll
                for (int r = 0; r < 4; ++r)
                    s[n][r] = __builtin_amdgcn_exp2f(s[n][r]);

            if (kbase + 63 > qrow0) {
                const int cb = kbase + quad * 4;
#pragma unroll
                for (int n = 0; n < 4; ++n)
#pragma unroll
                    for (int r = 0; r < 4; ++r)
                        if (cb + n * 16 + r > qrow) s[n][r] = 0.f;
            }

#pragma unroll
            for (int n = 0; n < 4; ++n)
                lacc += (s[n][0] + s[n][1]) + (s[n][2] + s[n][3]);

            // PV: pack A-frag locally (k-order matches phi-swizzled V), B = b128
#pragma unroll
            for (int st = 0; st < 2; ++st) {
                int4 ai = make_int4(
                    (int)pk2bf(s[2 * st][0],     s[2 * st][1]),
                    (int)pk2bf(s[2 * st][2],     s[2 * st][3]),
                    (int)pk2bf(s[2 * st + 1][0], s[2 * st + 1][1]),
                    (int)pk2bf(s[2 * st + 1][2], s[2 * st + 1][3]));
                short8 af = *(short8*)&ai;
                __builtin_amdgcn_s_setprio(1);
#pragma unroll
                for (int n = 0; n < 4; ++n) {
                    short8 bv = *(const short8*)&Vs[cur][n * 16 + l16][32 * st + quad * 8];
                    o[n] = __builtin_amdgcn_mfma_f32_16x16x32_bf16(af, bv, o[n], 0, 0, 0);
                }
                __builtin_amdgcn_s_setprio(0);
            }
        }

        if (p + 1 < np) {                // stage next tile into the other buffer
            const int nxt = cur ^ 1;
            *(short8*)&Ks[nxt][sr][scK] = kra;
            stage_v8(Vs[nxt], sr, pos0, vra);
        }
    }

    // reduce l over the quad dimension (q-row = l16 per lane)
    lacc += __shfl_xor(lacc, 16);
    lacc += __shfl_xor(lacc, 32);

    const int pid = blockIdx.x;
#pragma unroll
    for (int n = 0; n < 4; ++n)
#pragma unroll
        for (int r = 0; r < 4; ++r) {
            int lr = wave * 16 + quad * 4 + r;          // 0..127
            po[(size_t)pid * 8192 + lr * 64 + n * 16 + l16] = f2bf(o[n][r]);
        }
    if (quad == 0)
        pl[pid * 128 + wave * 16 + l16] = lacc;
}

// ---------------- Combine: sum <=8 bf16 partials, normalize ----------------
// pid mapping matches attn1's LPT-reversed e decode: pid(b,e) = b*EPB+(EPB-1-e)
__global__ __launch_bounds__(256) void combine_kernel(
    const unsigned short* __restrict__ po, const float* __restrict__ pl,
    float* __restrict__ out)
{
    const int gth = blockIdx.x * 256 + threadIdx.x;   // octet index, 131072 total
    const int h8  = gth & 7;
    const int row = gth >> 3;
    const int lr  = row & 127;
    const int Q   = (row >> 7) & 31;
    const int b   = row >> 12;
    const int g   = Q >> 2;
    const int rem = Q & 3;
    const int nc  = g + 1;
    const int e0  = 2 * g * (g + 1) + rem * (g + 1);
    const int pid0 = b * EPB + (EPB - 1 - e0);        // chunk cc lives at pid0-cc

    float l = 0.f;
    float acc[8];
#pragma unroll
    for (int i = 0; i < 8; ++i) acc[i] = 0.f;
    for (int cc = 0; cc < nc; ++cc) {
        l += pl[(pid0 - cc) * 128 + lr];
        short8 p8 = *(const short8*)(po + (size_t)(pid0 - cc) * 8192 + lr * 64 + h8 * 8);
#pragma unroll
        for (int i = 0; i < 8; ++i) acc[i] += bf2f((unsigned short)p8[i]);
    }
    float inv = 1.f / l;
    float4 r0 = make_float4(acc[0] * inv, acc[1] * inv, acc[2] * inv, acc[3] * inv);
    float4 r1 = make_float4(acc[4] * inv, acc[5] * inv, acc[6] * inv, acc[7] * inv);
    float* dst = out + (size_t)gth * 8;
    *(float4*)dst       = r0;
    *(float4*)(dst + 4) = r1;
}

extern "C" void kernel_launch(void* const* d_in, const int* in_sizes, int n_in,
                              void* d_out, int out_size, void* d_ws, size_t ws_size,
                              hipStream_t stream) {
    const float* x  = (const float*)d_in[0];
    const float* Wq = (const float*)d_in[1];
    const float* Wk = (const float*)d_in[2];
    const float* Wv = (const float*)d_in[3];
    float* out = (float*)d_out;

    char* ws = (char*)d_ws;
    unsigned short* qb = (unsigned short*)(ws);                 // 2 MB
    unsigned short* kb = (unsigned short*)(ws + (2u << 20));    // 2 MB
    unsigned short* vt = (unsigned short*)(ws + (4u << 20));    // 2 MB
    unsigned short* wt2 = (unsigned short*)(ws + (6u << 20));   // 192 KB
    float* pl = (float*)(ws + (6u << 20) + 196608);             // 294912 B
    unsigned short* po = (unsigned short*)(ws + (6u << 20) + 196608 + 294912); // 9.4 MB

    wcvt_kernel<<<dim3(192), dim3(64), 0, stream>>>(Wq, Wk, Wv, wt2);
    proj_kernel<<<dim3(512), dim3(512), 0, stream>>>(x, wt2, qb, kb, vt);
    attn1_kernel<<<dim3(NBATCH * EPB), dim3(512), 0, stream>>>(qb, kb, vt, po, pl);
    combine_kernel<<<dim3(512), dim3(256), 0, stream>>>(po, pl, out);
}